// Round 11
// baseline (518.309 us; speedup 1.0000x reference)
//
#include <hip/hip_runtime.h>
#include <hip/hip_bf16.h>
#include <cstdio>

#define U_N 100000
#define I_N 50000
#define H_DIM 128
#define E_N 600000
#define EL_N 200000

#define EPB 2048                         // edges per block in binning passes
#define NBLK ((E_N + EPB - 1) / EPB)     // 293
#define SH_U 8
#define SH_I 7
#define NB_U ((U_N + 255) >> 8)          // 391
#define NB_I ((I_N + 127) >> 7)          // 391
#define LH_U (NB_U * NBLK)               // 114563
#define LH_I (NB_I * NBLK)
#define LH_TOT (LH_U + LH_I)             // 229126
#define SCAN_BLKS ((LH_TOT + 1023) / 1024)  // 224

#define CVT_BLK (((U_N + I_N) * 16) / 256)  // 9375 exact
#define PREP_BLK 512
#define NBU3 ((U_N + 127) / 128)         // 782
#define NBI3 ((I_N + 127) / 128)         // 391

typedef __attribute__((ext_vector_type(8))) short bh8;
typedef __attribute__((ext_vector_type(4))) float f32x4;
typedef __attribute__((ext_vector_type(8))) unsigned short u16x8;

// fp32 -> bf16 (RNE)
__device__ inline unsigned short f2b(float f) {
  unsigned u = __builtin_bit_cast(unsigned, f);
  u += 0x7fffu + ((u >> 16) & 1u);
  return (unsigned short)(u >> 16);
}
// bf16 bits -> fp32
__device__ inline float b2f(unsigned short h) {
  unsigned u = ((unsigned)h) << 16;
  return __builtin_bit_cast(float, u);
}

// ---------------- fused prep: emb convert + weight prep + coarse histogram --
__global__ __launch_bounds__(256) void prep_all(
    const float* __restrict__ xu, const float* __restrict__ xi,
    const int* __restrict__ unid, const int* __restrict__ inid,
    unsigned short* __restrict__ ub, unsigned short* __restrict__ ib,
    const float* __restrict__ l0, const float* __restrict__ r0, short* __restrict__ o0,
    const float* __restrict__ l1, const float* __restrict__ r1, short* __restrict__ o1,
    const float* __restrict__ l2, const float* __restrict__ r2, short* __restrict__ o2,
    const float* __restrict__ l3, const float* __restrict__ r3, short* __restrict__ o3,
    const int* __restrict__ e_ui, int* __restrict__ hist, int* __restrict__ fv) {
  __shared__ int h[512];
  const int b = blockIdx.x;
  const int tid = threadIdx.x;
  if (b < CVT_BLK) {
    int t = b * 256 + tid;
    const float* x;
    unsigned short* xb;
    int row, seg;
    if (t < U_N * 16) {
      row = t >> 4; seg = t & 15;
      int r0_ = row;
      row = unid ? unid[row] : row;
      x = xu; xb = ub + (size_t)r0_ * H_DIM;
    } else {
      int t2 = t - U_N * 16;
      row = t2 >> 4; seg = t2 & 15;
      int r0_ = row;
      row = inid ? inid[row] : row;
      x = xi; xb = ib + (size_t)r0_ * H_DIM;
    }
    const float* p = x + (size_t)row * H_DIM + seg * 8;
    float4 a = ((const float4*)p)[0];
    float4 c = ((const float4*)p)[1];
    u16x8 v;
    v[0] = f2b(a.x); v[1] = f2b(a.y); v[2] = f2b(a.z); v[3] = f2b(a.w);
    v[4] = f2b(c.x); v[5] = f2b(c.y); v[6] = f2b(c.z); v[7] = f2b(c.w);
    *(u16x8*)(xb + seg * 8) = v;
  } else if (b < CVT_BLK + PREP_BLK) {
    int t = (b - CVT_BLK) * 256 + tid;  // 4*32768
    int set = t >> 15, s = t & 32767;
    const float *wl, *wr; short* W2;
    if (set == 0)      { wl = l0; wr = r0; W2 = o0; }
    else if (set == 1) { wl = l1; wr = r1; W2 = o1; }
    else if (set == 2) { wl = l2; wr = r2; W2 = o2; }
    else               { wl = l3; wr = r3; W2 = o3; }
    int col = s >> 8, k = s & 255;
    float v = (k < 128) ? wl[k * 128 + col] : wr[(k - 128) * 128 + col];
    W2[col * 256 + k] = (short)f2b(v);
  } else {
    int hb = b - CVT_BLK - PREP_BLK;          // [0, 2*NBLK)
    if (hb == 0 && tid < SCAN_BLKS) fv[tid] = 0;  // zero scan flags (ws is poisoned)
    int side = hb >= NBLK;
    int blk = side ? hb - NBLK : hb;
    const int* dst = e_ui + (side ? E_N : 0);
    int shift = side ? SH_I : SH_U;
    int nbins = side ? NB_I : NB_U;
    int hbase = side ? LH_U : 0;
    for (int i = tid; i < nbins; i += 256) h[i] = 0;
    __syncthreads();
    const int base = blk * EPB;
    const int end = min(base + EPB, E_N);
    for (int i = base + tid; i < end; i += 256)
      atomicAdd(&h[((unsigned)dst[i]) >> shift], 1);
    __syncthreads();
    for (int i = tid; i < nbins; i += 256)
      hist[hbase + i * NBLK + blk] = h[i];
  }
}

// ---------------- single-pass chained exclusive scan over LH_TOT ------------
// 224 blocks, all co-resident on 256 CUs -> spin on predecessor is safe.
// fv[b] holds (inclusive_prefix + 1); 0 = not yet published.
__global__ __launch_bounds__(256) void scan_chain(const int* __restrict__ hist,
                                                  int* __restrict__ hoff,
                                                  int* __restrict__ fv, int n) {
  const int b = blockIdx.x;
  const int t = threadIdx.x;
  const int lane = t & 63, wv = t >> 6;
  const int base = b * 1024 + t * 4;
  int vals[4];
  int s = 0;
  for (int j = 0; j < 4; ++j) {
    int i = base + j;
    vals[j] = (i < n) ? hist[i] : 0;
    s += vals[j];
  }
  int inc = s;
  for (int d = 1; d < 64; d <<= 1) {
    int x = __shfl_up(inc, d, 64);
    if (lane >= d) inc += x;
  }
  __shared__ int wsum[4];
  __shared__ int sprev;
  if (lane == 63) wsum[wv] = inc;
  __syncthreads();
  if (t == 0) {
    int S = wsum[0] + wsum[1] + wsum[2] + wsum[3];
    int prev = 0;
    if (b > 0) {
      int v;
      do { v = atomicAdd(&fv[b - 1], 0); } while (v == 0);
      prev = v - 1;
    }
    atomicExch(&fv[b], prev + S + 1);
    sprev = prev;
  }
  __syncthreads();
  int wbase = 0;
  for (int w = 0; w < wv; ++w) wbase += wsum[w];
  int excl = sprev + wbase + (inc - s);
  for (int j = 0; j < 4; ++j) {
    int i = base + j;
    if (i < n) hoff[i] = excl;
    excl += vals[j];
  }
}

// ---------------- scatter packed (dstlo|src) into combined buckets ----------
__global__ __launch_bounds__(256) void bin_scatter2(const int* __restrict__ e_ui,
                                                    const int* __restrict__ hoff,
                                                    unsigned* __restrict__ bucketed) {
  __shared__ int cur[512];
  const int t = threadIdx.x;
  const int hb = blockIdx.x;                 // [0, 2*NBLK)
  const int side = hb >= NBLK;
  const int blk = side ? hb - NBLK : hb;
  const int* dst = e_ui + (side ? E_N : 0);
  const int* src = e_ui + (side ? 0 : E_N);
  const int shift = side ? SH_I : SH_U;
  const int nbins = side ? NB_I : NB_U;
  const int hbase = side ? LH_U : 0;
  for (int i = t; i < nbins; i += 256) cur[i] = hoff[hbase + i * NBLK + blk];
  __syncthreads();
  const int base = blk * EPB;
  const int end = min(base + EPB, E_N);
  const unsigned mask = (1u << shift) - 1u;
  for (int i = base + t; i < end; i += 256) {
    unsigned d = (unsigned)dst[i];
    int bin = (int)(d >> shift);
    int pos = atomicAdd(&cur[bin], 1);
    bucketed[pos] = ((d & mask) << 24) | (unsigned)src[i];
  }
}

// ---------------- group bucket by exact dst -> csr (combined), cnt, off -----
__global__ __launch_bounds__(256) void bin_group2(const int* __restrict__ hoff,
                                                  const unsigned* __restrict__ bucketed,
                                                  int* __restrict__ csr,
                                                  int* __restrict__ cnt_u,
                                                  int* __restrict__ off_u,
                                                  int* __restrict__ cnt_i,
                                                  int* __restrict__ off_i) {
  __shared__ int cl[256];
  __shared__ int cur[256];
  __shared__ int wsum[4];
  const int b = blockIdx.x;
  const int t = threadIdx.x;
  const int side = b >= NB_U;
  const int bb = side ? b - NB_U : b;
  const int shift = side ? SH_I : SH_U;
  const int N = side ? I_N : U_N;
  int* cnt = side ? cnt_i : cnt_u;
  int* off = side ? off_i : off_u;
  int start, end;
  if (!side) {
    start = hoff[bb * NBLK];
    end = (bb + 1 < NB_U) ? hoff[(bb + 1) * NBLK] : E_N;
  } else {
    start = hoff[LH_U + bb * NBLK];
    end = (bb + 1 < NB_I) ? hoff[LH_U + (bb + 1) * NBLK] : 2 * E_N;
  }
  const int ndst = 1 << shift;   // 256 (users) or 128 (items)
  const int base = bb << shift;
  if (t < ndst) cl[t] = 0;
  __syncthreads();
  for (int i = start + t; i < end; i += 256)
    atomicAdd(&cl[bucketed[i] >> 24], 1);
  __syncthreads();
  int v = (t < ndst) ? cl[t] : 0;
  const int lane = t & 63, wv = t >> 6;
  int inc = v;
  for (int d = 1; d < 64; d <<= 1) {
    int x = __shfl_up(inc, d, 64);
    if (lane >= d) inc += x;
  }
  if (lane == 63) wsum[wv] = inc;
  __syncthreads();
  int wbase = 0;
  for (int q = 0; q < wv; ++q) wbase += wsum[q];
  int excl = wbase + inc - v;
  if (t < ndst) {
    cur[t] = start + excl;
    int node = base + t;
    if (node < N) { cnt[node] = v; off[node] = start + excl; }
  }
  __syncthreads();
  for (int i = start + t; i < end; i += 256) {
    unsigned w = bucketed[i];
    int pos = atomicAdd(&cur[w >> 24], 1);
    csr[pos] = (int)(w & 0xFFFFFFu);
  }
}

// ---------------- gather-mean, both sides (bf16 in, bf16 mean out) ----------
// 16-lane group per destination node; 16B/lane (u16x8) reads; x4 ILP unroll.
// NOTE: ILP-4 (not 8) is deliberate — ILP-8 raised VGPR 32->48, occupancy
// 62%->41%, and ran *slower* (R8 post-mortem). This kernel is latency-bound
// and wants maximal wave residency. Stable ~47 us across 3 structural
// variants => treated as the random-row fabric floor (~2.7 TB/s HBM-side).
__global__ __launch_bounds__(256) void gather_mean2(
    const int* __restrict__ off_u, const int* __restrict__ cnt_u,
    const unsigned short* __restrict__ xsrc_u, unsigned short* __restrict__ agg_u,
    const int* __restrict__ off_i, const int* __restrict__ cnt_i,
    const unsigned short* __restrict__ xsrc_i, unsigned short* __restrict__ agg_i,
    const int* __restrict__ csr) {
  long t = (long)blockIdx.x * 256 + threadIdx.x;
  int node = (int)(t >> 4);
  int lane = (int)(t & 15);
  const int* off; const int* cnt;
  const unsigned short* xb; unsigned short* aggb;
  if (node < U_N) {
    off = off_u; cnt = cnt_u; xb = xsrc_u; aggb = agg_u;
  } else {
    node -= U_N;
    if (node >= I_N) return;
    off = off_i; cnt = cnt_i; xb = xsrc_i; aggb = agg_i;
  }
  int o = off[node], c = cnt[node];
  float acc[8] = {};
  for (int j0 = 0; j0 < c; j0 += 16) {
    int nj = c - j0;
    if (nj > 16) nj = 16;
    int sidx = (lane < nj) ? csr[o + j0 + lane] : 0;
    int j = 0;
    for (; j + 4 <= nj; j += 4) {
      u16x8 v0, v1, v2, v3;
      {
        int s0 = __shfl(sidx, j + 0, 16);
        int s1 = __shfl(sidx, j + 1, 16);
        int s2 = __shfl(sidx, j + 2, 16);
        int s3 = __shfl(sidx, j + 3, 16);
        v0 = *(const u16x8*)(xb + (size_t)s0 * H_DIM + lane * 8);
        v1 = *(const u16x8*)(xb + (size_t)s1 * H_DIM + lane * 8);
        v2 = *(const u16x8*)(xb + (size_t)s2 * H_DIM + lane * 8);
        v3 = *(const u16x8*)(xb + (size_t)s3 * H_DIM + lane * 8);
      }
      for (int k = 0; k < 8; ++k) acc[k] += b2f(v0[k]);
      for (int k = 0; k < 8; ++k) acc[k] += b2f(v1[k]);
      for (int k = 0; k < 8; ++k) acc[k] += b2f(v2[k]);
      for (int k = 0; k < 8; ++k) acc[k] += b2f(v3[k]);
    }
    for (; j < nj; ++j) {
      int s = __shfl(sidx, j, 16);
      u16x8 v = *(const u16x8*)(xb + (size_t)s * H_DIM + lane * 8);
      for (int k = 0; k < 8; ++k) acc[k] += b2f(v[k]);
    }
  }
  float inv = 1.0f / (float)(c > 0 ? c : 1);
  u16x8 r;
  for (int k = 0; k < 8; ++k) r[k] = f2b(acc[k] * inv);
  *(u16x8*)(aggb + (size_t)node * H_DIM + lane * 8) = r;
}

// ---------------- SAGE linear, LDS-free: B-fragments in VGPRs ---------------
// out = act( mean@w_l + x@w_r + b ). 128 rows/block; wave w covers output
// col-blocks {2w, 2w+1} (bfrag 64 VGPR). Per-row-group epilogue keeps acc
// liveness at 8 VGPR. No LDS, no barriers -> better occupancy than the
// 64KB-LDS variant (R9 validated B-in-VGPR MFMA correctness).
__global__ __launch_bounds__(256) void sage_gemm3(
    const unsigned short* __restrict__ agg_u, const unsigned short* __restrict__ x_u,
    const short* __restrict__ W2_u, const float* __restrict__ bias_u,
    unsigned short* __restrict__ out_u,
    const unsigned short* __restrict__ agg_i, const unsigned short* __restrict__ x_i,
    const short* __restrict__ W2_i, const float* __restrict__ bias_i,
    unsigned short* __restrict__ out_i, int relu) {
  const unsigned short *aggb, *xb;
  const short* W2;
  const float* bias;
  unsigned short* outb;
  int N, blk;
  if (blockIdx.x < NBU3) {
    aggb = agg_u; xb = x_u; W2 = W2_u; bias = bias_u; outb = out_u;
    N = U_N; blk = blockIdx.x;
  } else {
    aggb = agg_i; xb = x_i; W2 = W2_i; bias = bias_i; outb = out_i;
    N = I_N; blk = blockIdx.x - NBU3;
  }
  const int tid = threadIdx.x;
  const int lane = tid & 63, wave = tid >> 6;
  const int n16 = lane & 15, q = lane >> 4;
  const int rowbase = blk * 128;

  // B fragments for col-blocks 2w, 2w+1 (W2 is L2-resident)
  bh8 bfrag[8][2];
  for (int kt = 0; kt < 8; ++kt)
    for (int j = 0; j < 2; ++j)
      bfrag[kt][j] = *(const bh8*)(W2 + ((wave * 2 + j) * 16 + n16) * 256 + kt * 32 + q * 8);

  float bc[2];
  bc[0] = bias[(wave * 2 + 0) * 16 + n16];
  bc[1] = bias[(wave * 2 + 1) * 16 + n16];

  for (int g = 0; g < 8; ++g) {
    int row = rowbase + g * 16 + n16;
    int rr = row < N ? row : N - 1;
    const unsigned short* ap = aggb + (size_t)rr * H_DIM + q * 8;
    const unsigned short* xp = xb + (size_t)rr * H_DIM + q * 8;
    f32x4 acc[2] = {};
    for (int kt = 0; kt < 8; ++kt) {
      const unsigned short* p = (kt < 4) ? (ap + kt * 32) : (xp + (kt - 4) * 32);
      bh8 a = *(const bh8*)(p);
      acc[0] = __builtin_amdgcn_mfma_f32_16x16x32_bf16(a, bfrag[kt][0], acc[0], 0, 0, 0);
      acc[1] = __builtin_amdgcn_mfma_f32_16x16x32_bf16(a, bfrag[kt][1], acc[1], 0, 0, 0);
    }
    for (int r = 0; r < 4; ++r) {
      int orow = rowbase + g * 16 + q * 4 + r;
      if (orow >= N) continue;
      for (int j = 0; j < 2; ++j) {
        float v = acc[j][r] + bc[j];
        if (relu) v = v > 0.0f ? v : 0.0f;
        outb[(size_t)orow * H_DIM + (wave * 2 + j) * 16 + n16] = f2b(v);
      }
    }
  }
}

// ---------------- final edge dot product (bf16 h2, 16 lanes/edge) -----------
__global__ __launch_bounds__(256) void final_dot(const int* __restrict__ lbl,
                                                 const unsigned short* __restrict__ u2,
                                                 const unsigned short* __restrict__ i2,
                                                 float* __restrict__ out) {
  long t = (long)blockIdx.x * 256 + threadIdx.x;
  int e = (int)(t >> 4);
  if (e >= EL_N) return;
  int lane = (int)(t & 15);
  int lu = lbl[e];
  int li = lbl[EL_N + e];
  u16x8 a = *(const u16x8*)(u2 + (size_t)lu * H_DIM + lane * 8);
  u16x8 b = *(const u16x8*)(i2 + (size_t)li * H_DIM + lane * 8);
  float p = 0.f;
  for (int k = 0; k < 8; ++k) p += b2f(a[k]) * b2f(b[k]);
  for (int off = 8; off > 0; off >>= 1) p += __shfl_down(p, off, 16);
  if (lane == 0) out[e] = p;
}

extern "C" void kernel_launch(void* const* d_in, const int* in_sizes, int n_in,
                              void* d_out, int out_size, void* d_ws, size_t ws_size,
                              hipStream_t stream) {
  const float* user_emb = (const float*)d_in[0];
  const float* item_emb = (const float*)d_in[1];
  const float* w1_ui_l = (const float*)d_in[2];
  const float* w1_ui_r = (const float*)d_in[3];
  const float* w1_iu_l = (const float*)d_in[4];
  const float* w1_iu_r = (const float*)d_in[5];
  const float* w2_ui_l = (const float*)d_in[6];
  const float* w2_ui_r = (const float*)d_in[7];
  const float* w2_iu_l = (const float*)d_in[8];
  const float* w2_iu_r = (const float*)d_in[9];
  const float* b1_ui = (const float*)d_in[10];
  const float* b1_iu = (const float*)d_in[11];
  const float* b2_ui = (const float*)d_in[12];
  const float* b2_iu = (const float*)d_in[13];
  const int* unid = (const int*)d_in[14];
  const int* inid = (const int*)d_in[15];
  const int* e_ui = (const int*)d_in[16];  // row0 users, row1 items
  const int* e_iu = (const int*)d_in[17];  // row0 items, row1 users
  const int* elbl = (const int*)d_in[18];  // row0 users, row1 items
  float* out = (float*)d_out;

  char* ws = (char*)d_ws;
  size_t o = 0;
  auto alloc = [&](size_t bytes) {
    char* p = ws + o;
    o = (o + bytes + 255) & ~(size_t)255;
    return p;
  };
  int* hist = (int*)alloc((size_t)LH_TOT * 4);
  int* hoff = (int*)alloc((size_t)LH_TOT * 4);
  unsigned* bkt = (unsigned*)alloc((size_t)2 * E_N * 4);
  int* csr = (int*)alloc((size_t)2 * E_N * 4);   // u-region [0,E_N), i-region [E_N,2E_N)
  int* cnt_u = (int*)alloc((size_t)U_N * 4);
  int* cnt_i = (int*)alloc((size_t)I_N * 4);
  int* off_u = (int*)alloc((size_t)U_N * 4);
  int* off_i = (int*)alloc((size_t)I_N * 4);
  int* fv = (int*)alloc(SCAN_BLKS * 4);
  unsigned short* ue_b = (unsigned short*)alloc((size_t)U_N * H_DIM * 2);
  unsigned short* ie_b = (unsigned short*)alloc((size_t)I_N * H_DIM * 2);
  unsigned short* agg_u = (unsigned short*)alloc((size_t)U_N * H_DIM * 2);
  unsigned short* agg_i = (unsigned short*)alloc((size_t)I_N * H_DIM * 2);
  unsigned short* h1_u = (unsigned short*)alloc((size_t)U_N * H_DIM * 2);
  unsigned short* h1_i = (unsigned short*)alloc((size_t)I_N * H_DIM * 2);
  unsigned short* h2_u = (unsigned short*)alloc((size_t)U_N * H_DIM * 2);
  unsigned short* h2_i = (unsigned short*)alloc((size_t)I_N * H_DIM * 2);
  short* W2_1u = (short*)alloc(128 * 256 * 2);
  short* W2_1i = (short*)alloc(128 * 256 * 2);
  short* W2_2u = (short*)alloc(128 * 256 * 2);
  short* W2_2i = (short*)alloc(128 * 256 * 2);
  if (o > ws_size) {
    fprintf(stderr, "kernel_launch: ws too small, need %zu have %zu\n", o, ws_size);
    return;
  }

  // 1) fused prep: cvt + weights + coarse histogram (+ scan-flag zeroing)
  prep_all<<<CVT_BLK + PREP_BLK + 2 * NBLK, 256, 0, stream>>>(
      user_emb, item_emb, unid, inid, ue_b, ie_b,
      w1_iu_l, w1_iu_r, W2_1u, w1_ui_l, w1_ui_r, W2_1i,
      w2_iu_l, w2_iu_r, W2_2u, w2_ui_l, w2_ui_r, W2_2i,
      e_ui, hist, fv);

  // 2) single-pass chained scan of concatenated histogram
  scan_chain<<<SCAN_BLKS, 256, 0, stream>>>(hist, hoff, fv, LH_TOT);

  // 3) scatter into combined buckets, 4) group -> combined csr + cnt/off
  bin_scatter2<<<2 * NBLK, 256, 0, stream>>>(e_ui, hoff, bkt);
  bin_group2<<<NB_U + NB_I, 256, 0, stream>>>(hoff, bkt, csr, cnt_u, off_u, cnt_i, off_i);

  const int g_blocks = ((U_N + I_N) * 16 + 255) / 256;
  // 5-6) layer 1
  gather_mean2<<<g_blocks, 256, 0, stream>>>(off_u, cnt_u, ie_b, agg_u,
                                             off_i, cnt_i, ue_b, agg_i, csr);
  sage_gemm3<<<NBU3 + NBI3, 256, 0, stream>>>(
      agg_u, ue_b, W2_1u, b1_iu, h1_u,
      agg_i, ie_b, W2_1i, b1_ui, h1_i, 1);

  // 7-8) layer 2 (reuse CSR)
  gather_mean2<<<g_blocks, 256, 0, stream>>>(off_u, cnt_u, h1_i, agg_u,
                                             off_i, cnt_i, h1_u, agg_i, csr);
  sage_gemm3<<<NBU3 + NBI3, 256, 0, stream>>>(
      agg_u, h1_u, W2_2u, b2_iu, h2_u,
      agg_i, h1_i, W2_2i, b2_ui, h2_i, 0);

  // 9) classifier
  final_dot<<<(EL_N * 16 + 255) / 256, 256, 0, stream>>>(elbl, h2_u, h2_i, out);
}

// Round 12
// 356.893 us; speedup vs baseline: 1.4523x; 1.4523x over previous
//
#include <hip/hip_runtime.h>
#include <hip/hip_bf16.h>
#include <cstdio>

#define U_N 100000
#define I_N 50000
#define H_DIM 128
#define E_N 600000
#define EL_N 200000

#define EPB 2048                         // edges per block in binning passes
#define NBLK ((E_N + EPB - 1) / EPB)     // 293
#define SH_U 8
#define SH_I 7
#define NB_U ((U_N + 255) >> 8)          // 391
#define NB_I ((I_N + 127) >> 7)          // 391
#define LH_U (NB_U * NBLK)               // 114563
#define LH_I (NB_I * NBLK)
#define LH_TOT (LH_U + LH_I)             // 229126
#define SCAN_BLKS ((LH_TOT + 1023) / 1024)  // 224

#define CVT_BLK (((U_N + I_N) * 16) / 256)  // 9375 exact
#define PREP_BLK 512
#define NBU2 ((U_N + 255) / 256)         // 391
#define NBI2 ((I_N + 255) / 256)         // 196

typedef __attribute__((ext_vector_type(8))) short bh8;
typedef __attribute__((ext_vector_type(4))) float f32x4;
typedef __attribute__((ext_vector_type(8))) unsigned short u16x8;

// fp32 -> bf16 (RNE)
__device__ inline unsigned short f2b(float f) {
  unsigned u = __builtin_bit_cast(unsigned, f);
  u += 0x7fffu + ((u >> 16) & 1u);
  return (unsigned short)(u >> 16);
}
// bf16 bits -> fp32
__device__ inline float b2f(unsigned short h) {
  unsigned u = ((unsigned)h) << 16;
  return __builtin_bit_cast(float, u);
}

// ---------------- fused prep: emb convert + weight prep + coarse histogram --
__global__ __launch_bounds__(256) void prep_all(
    const float* __restrict__ xu, const float* __restrict__ xi,
    const int* __restrict__ unid, const int* __restrict__ inid,
    unsigned short* __restrict__ ub, unsigned short* __restrict__ ib,
    const float* __restrict__ l0, const float* __restrict__ r0, short* __restrict__ o0,
    const float* __restrict__ l1, const float* __restrict__ r1, short* __restrict__ o1,
    const float* __restrict__ l2, const float* __restrict__ r2, short* __restrict__ o2,
    const float* __restrict__ l3, const float* __restrict__ r3, short* __restrict__ o3,
    const int* __restrict__ e_ui, int* __restrict__ hist) {
  __shared__ int h[512];
  const int b = blockIdx.x;
  const int tid = threadIdx.x;
  if (b < CVT_BLK) {
    int t = b * 256 + tid;
    const float* x;
    unsigned short* xb;
    int row, seg;
    if (t < U_N * 16) {
      row = t >> 4; seg = t & 15;
      int r0_ = row;
      row = unid ? unid[row] : row;
      x = xu; xb = ub + (size_t)r0_ * H_DIM;
    } else {
      int t2 = t - U_N * 16;
      row = t2 >> 4; seg = t2 & 15;
      int r0_ = row;
      row = inid ? inid[row] : row;
      x = xi; xb = ib + (size_t)r0_ * H_DIM;
    }
    const float* p = x + (size_t)row * H_DIM + seg * 8;
    float4 a = ((const float4*)p)[0];
    float4 c = ((const float4*)p)[1];
    u16x8 v;
    v[0] = f2b(a.x); v[1] = f2b(a.y); v[2] = f2b(a.z); v[3] = f2b(a.w);
    v[4] = f2b(c.x); v[5] = f2b(c.y); v[6] = f2b(c.z); v[7] = f2b(c.w);
    *(u16x8*)(xb + seg * 8) = v;
  } else if (b < CVT_BLK + PREP_BLK) {
    int t = (b - CVT_BLK) * 256 + tid;  // 4*32768
    int set = t >> 15, s = t & 32767;
    const float *wl, *wr; short* W2;
    if (set == 0)      { wl = l0; wr = r0; W2 = o0; }
    else if (set == 1) { wl = l1; wr = r1; W2 = o1; }
    else if (set == 2) { wl = l2; wr = r2; W2 = o2; }
    else               { wl = l3; wr = r3; W2 = o3; }
    int col = s >> 8, k = s & 255;
    float v = (k < 128) ? wl[k * 128 + col] : wr[(k - 128) * 128 + col];
    W2[col * 256 + k] = (short)f2b(v);
  } else {
    int hb = b - CVT_BLK - PREP_BLK;          // [0, 2*NBLK)
    int side = hb >= NBLK;
    int blk = side ? hb - NBLK : hb;
    const int* dst = e_ui + (side ? E_N : 0);
    int shift = side ? SH_I : SH_U;
    int nbins = side ? NB_I : NB_U;
    int hbase = side ? LH_U : 0;
    for (int i = tid; i < nbins; i += 256) h[i] = 0;
    __syncthreads();
    const int base = blk * EPB;
    const int end = min(base + EPB, E_N);
    for (int i = base + tid; i < end; i += 256)
      atomicAdd(&h[((unsigned)dst[i]) >> shift], 1);
    __syncthreads();
    for (int i = tid; i < nbins; i += 256)
      hist[hbase + i * NBLK + blk] = h[i];
  }
}

// ---------------- 2-dispatch hierarchical exclusive scan --------------------
// p1: per-1024-tile sums. p3: each block scans the <=224 tile sums itself
// (redundant but cheap: 224 ints), then local scan + write. No p2 dispatch.
// NOTE (R11 post-mortem): a chained single-pass scan (spin on device-scope
// atomic across 224 blocks) took 129 us — ~580 ns per chain link through the
// fabric. Never serialize blocks via device atomics on MI355X.
__global__ __launch_bounds__(256) void scan_p1(const int* __restrict__ cnt,
                                               int* __restrict__ bsum, int n) {
  const int t = threadIdx.x;
  const int base = blockIdx.x * 1024 + t * 4;
  int s = 0;
  for (int j = 0; j < 4; ++j) {
    int i = base + j;
    if (i < n) s += cnt[i];
  }
  for (int off = 32; off > 0; off >>= 1) s += __shfl_down(s, off, 64);
  __shared__ int wsum[4];
  if ((t & 63) == 0) wsum[t >> 6] = s;
  __syncthreads();
  if (t == 0) bsum[blockIdx.x] = wsum[0] + wsum[1] + wsum[2] + wsum[3];
}

__global__ __launch_bounds__(256) void scan_p3(const int* __restrict__ cnt,
                                               const int* __restrict__ bsum,
                                               int* __restrict__ off, int n, int nb) {
  const int t = threadIdx.x;
  const int lane = t & 63, wv = t >> 6;
  __shared__ int sm[256];
  __shared__ int wsum[4];
  // block-base: exclusive prefix of bsum[0..blockIdx.x)
  {
    int v = (t < nb) ? bsum[t] : 0;
    sm[t] = v;
    __syncthreads();
    for (int d = 1; d < 256; d <<= 1) {
      int x = (t >= d) ? sm[t - d] : 0;
      __syncthreads();
      sm[t] += x;
      __syncthreads();
    }
  }
  const int blockbase = (blockIdx.x == 0) ? 0 : sm[blockIdx.x - 1];
  const int base = blockIdx.x * 1024 + t * 4;
  int vals[4];
  int s = 0;
  for (int j = 0; j < 4; ++j) {
    int i = base + j;
    vals[j] = (i < n) ? cnt[i] : 0;
    s += vals[j];
  }
  int inc = s;
  for (int d = 1; d < 64; d <<= 1) {
    int x = __shfl_up(inc, d, 64);
    if (lane >= d) inc += x;
  }
  if (lane == 63) wsum[wv] = inc;
  __syncthreads();
  int wbase = 0;
  for (int w = 0; w < wv; ++w) wbase += wsum[w];
  int excl = blockbase + wbase + (inc - s);
  for (int j = 0; j < 4; ++j) {
    int i = base + j;
    if (i < n) off[i] = excl;
    excl += vals[j];
  }
}

// ---------------- scatter packed (dstlo|src) into combined buckets ----------
__global__ __launch_bounds__(256) void bin_scatter2(const int* __restrict__ e_ui,
                                                    const int* __restrict__ hoff,
                                                    unsigned* __restrict__ bucketed) {
  __shared__ int cur[512];
  const int t = threadIdx.x;
  const int hb = blockIdx.x;                 // [0, 2*NBLK)
  const int side = hb >= NBLK;
  const int blk = side ? hb - NBLK : hb;
  const int* dst = e_ui + (side ? E_N : 0);
  const int* src = e_ui + (side ? 0 : E_N);
  const int shift = side ? SH_I : SH_U;
  const int nbins = side ? NB_I : NB_U;
  const int hbase = side ? LH_U : 0;
  for (int i = t; i < nbins; i += 256) cur[i] = hoff[hbase + i * NBLK + blk];
  __syncthreads();
  const int base = blk * EPB;
  const int end = min(base + EPB, E_N);
  const unsigned mask = (1u << shift) - 1u;
  for (int i = base + t; i < end; i += 256) {
    unsigned d = (unsigned)dst[i];
    int bin = (int)(d >> shift);
    int pos = atomicAdd(&cur[bin], 1);
    bucketed[pos] = ((d & mask) << 24) | (unsigned)src[i];
  }
}

// ---------------- group bucket by exact dst -> csr (combined), cnt, off -----
__global__ __launch_bounds__(256) void bin_group2(const int* __restrict__ hoff,
                                                  const unsigned* __restrict__ bucketed,
                                                  int* __restrict__ csr,
                                                  int* __restrict__ cnt_u,
                                                  int* __restrict__ off_u,
                                                  int* __restrict__ cnt_i,
                                                  int* __restrict__ off_i) {
  __shared__ int cl[256];
  __shared__ int cur[256];
  __shared__ int wsum[4];
  const int b = blockIdx.x;
  const int t = threadIdx.x;
  const int side = b >= NB_U;
  const int bb = side ? b - NB_U : b;
  const int shift = side ? SH_I : SH_U;
  const int N = side ? I_N : U_N;
  int* cnt = side ? cnt_i : cnt_u;
  int* off = side ? off_i : off_u;
  int start, end;
  if (!side) {
    start = hoff[bb * NBLK];
    end = (bb + 1 < NB_U) ? hoff[(bb + 1) * NBLK] : E_N;
  } else {
    start = hoff[LH_U + bb * NBLK];
    end = (bb + 1 < NB_I) ? hoff[LH_U + (bb + 1) * NBLK] : 2 * E_N;
  }
  const int ndst = 1 << shift;   // 256 (users) or 128 (items)
  const int base = bb << shift;
  if (t < ndst) cl[t] = 0;
  __syncthreads();
  for (int i = start + t; i < end; i += 256)
    atomicAdd(&cl[bucketed[i] >> 24], 1);
  __syncthreads();
  int v = (t < ndst) ? cl[t] : 0;
  const int lane = t & 63, wv = t >> 6;
  int inc = v;
  for (int d = 1; d < 64; d <<= 1) {
    int x = __shfl_up(inc, d, 64);
    if (lane >= d) inc += x;
  }
  if (lane == 63) wsum[wv] = inc;
  __syncthreads();
  int wbase = 0;
  for (int q = 0; q < wv; ++q) wbase += wsum[q];
  int excl = wbase + inc - v;
  if (t < ndst) {
    cur[t] = start + excl;
    int node = base + t;
    if (node < N) { cnt[node] = v; off[node] = start + excl; }
  }
  __syncthreads();
  for (int i = start + t; i < end; i += 256) {
    unsigned w = bucketed[i];
    int pos = atomicAdd(&cur[w >> 24], 1);
    csr[pos] = (int)(w & 0xFFFFFFu);
  }
}

// ---------------- gather-mean, both sides (bf16 in, bf16 mean out) ----------
// 16-lane group per destination node; 16B/lane (u16x8) reads; x4 ILP unroll.
// NOTE: ILP-4 (not 8) is deliberate — ILP-8 raised VGPR 32->48, occupancy
// 62%->41%, and ran *slower* (R8 post-mortem). This kernel is latency-bound
// and wants maximal wave residency. Stable ~47 us across 3 structural
// variants => treated as the random-row fabric floor (~2.7 TB/s HBM-side).
__global__ __launch_bounds__(256) void gather_mean2(
    const int* __restrict__ off_u, const int* __restrict__ cnt_u,
    const unsigned short* __restrict__ xsrc_u, unsigned short* __restrict__ agg_u,
    const int* __restrict__ off_i, const int* __restrict__ cnt_i,
    const unsigned short* __restrict__ xsrc_i, unsigned short* __restrict__ agg_i,
    const int* __restrict__ csr) {
  long t = (long)blockIdx.x * 256 + threadIdx.x;
  int node = (int)(t >> 4);
  int lane = (int)(t & 15);
  const int* off; const int* cnt;
  const unsigned short* xb; unsigned short* aggb;
  if (node < U_N) {
    off = off_u; cnt = cnt_u; xb = xsrc_u; aggb = agg_u;
  } else {
    node -= U_N;
    if (node >= I_N) return;
    off = off_i; cnt = cnt_i; xb = xsrc_i; aggb = agg_i;
  }
  int o = off[node], c = cnt[node];
  float acc[8] = {};
  for (int j0 = 0; j0 < c; j0 += 16) {
    int nj = c - j0;
    if (nj > 16) nj = 16;
    int sidx = (lane < nj) ? csr[o + j0 + lane] : 0;
    int j = 0;
    for (; j + 4 <= nj; j += 4) {
      u16x8 v0, v1, v2, v3;
      {
        int s0 = __shfl(sidx, j + 0, 16);
        int s1 = __shfl(sidx, j + 1, 16);
        int s2 = __shfl(sidx, j + 2, 16);
        int s3 = __shfl(sidx, j + 3, 16);
        v0 = *(const u16x8*)(xb + (size_t)s0 * H_DIM + lane * 8);
        v1 = *(const u16x8*)(xb + (size_t)s1 * H_DIM + lane * 8);
        v2 = *(const u16x8*)(xb + (size_t)s2 * H_DIM + lane * 8);
        v3 = *(const u16x8*)(xb + (size_t)s3 * H_DIM + lane * 8);
      }
      for (int k = 0; k < 8; ++k) acc[k] += b2f(v0[k]);
      for (int k = 0; k < 8; ++k) acc[k] += b2f(v1[k]);
      for (int k = 0; k < 8; ++k) acc[k] += b2f(v2[k]);
      for (int k = 0; k < 8; ++k) acc[k] += b2f(v3[k]);
    }
    for (; j < nj; ++j) {
      int s = __shfl(sidx, j, 16);
      u16x8 v = *(const u16x8*)(xb + (size_t)s * H_DIM + lane * 8);
      for (int k = 0; k < 8; ++k) acc[k] += b2f(v[k]);
    }
  }
  float inv = 1.0f / (float)(c > 0 ? c : 1);
  u16x8 r;
  for (int k = 0; k < 8; ++k) r[k] = f2b(acc[k] * inv);
  *(u16x8*)(aggb + (size_t)node * H_DIM + lane * 8) = r;
}

// ---------------- fused SAGE linear, both sides, 256 rows/block --------------
// out = act( mean@w_l + x@w_r + b ), all bf16 in/out, fp32 MFMA accum.
// NOTE (R11): LDS-free B-in-VGPR variant with 2 accumulators was slower —
// 8-deep dependent MFMA chains stall; this version's 32 independent acc
// chains keep the pipe full. Keep the 64KB-LDS weight stage.
__global__ __launch_bounds__(256, 2) void sage_gemm2(
    const unsigned short* __restrict__ agg_u, const unsigned short* __restrict__ x_u,
    const short* __restrict__ W2_u, const float* __restrict__ bias_u,
    unsigned short* __restrict__ out_u,
    const unsigned short* __restrict__ agg_i, const unsigned short* __restrict__ x_i,
    const short* __restrict__ W2_i, const float* __restrict__ bias_i,
    unsigned short* __restrict__ out_i, int relu) {
  const unsigned short *aggb, *xb;
  const short* W2;
  const float* bias;
  unsigned short* outb;
  int N, blk;
  if (blockIdx.x < NBU2) {
    aggb = agg_u; xb = x_u; W2 = W2_u; bias = bias_u; outb = out_u;
    N = U_N; blk = blockIdx.x;
  } else {
    aggb = agg_i; xb = x_i; W2 = W2_i; bias = bias_i; outb = out_i;
    N = I_N; blk = blockIdx.x - NBU2;
  }

  __shared__ short wlds[128 * 256];  // 64 KiB
  const int tid = threadIdx.x;
  for (int c = tid; c < 4096; c += 256) {
    int col = c >> 5, g = c & 31;
    uint4 v = *(const uint4*)(W2 + col * 256 + g * 8);
    *(uint4*)(&wlds[col * 256 + ((g ^ (col & 15)) * 8)]) = v;
  }
  __syncthreads();

  const int lane = tid & 63;
  const int wave = tid >> 6;
  const int q = lane >> 4;
  const int n16 = lane & 15;
  const int rowbase = blk * 256 + wave * 64;

  const unsigned short* aptr[4];
  const unsigned short* xptr[4];
  for (int g = 0; g < 4; ++g) {
    int row = rowbase + g * 16 + n16;
    int rr = row < N ? row : 0;
    aptr[g] = aggb + (size_t)rr * H_DIM + q * 8;
    xptr[g] = xb + (size_t)rr * H_DIM + q * 8;
  }

  f32x4 acc[4][8] = {};

  for (int kt = 0; kt < 8; ++kt) {
    const int k0 = kt * 32;
    bh8 afrag[4];
    for (int g = 0; g < 4; ++g) {
      const unsigned short* p = (kt < 4) ? (aptr[g] + k0) : (xptr[g] + (k0 - 128));
      afrag[g] = *(const bh8*)(p);
    }
    const int swz = ((kt * 4 + q) ^ n16) * 8;
    for (int c = 0; c < 8; ++c) {
      bh8 b = *(const bh8*)(&wlds[(c * 16 + n16) * 256 + swz]);
      acc[0][c] = __builtin_amdgcn_mfma_f32_16x16x32_bf16(afrag[0], b, acc[0][c], 0, 0, 0);
      acc[1][c] = __builtin_amdgcn_mfma_f32_16x16x32_bf16(afrag[1], b, acc[1][c], 0, 0, 0);
      acc[2][c] = __builtin_amdgcn_mfma_f32_16x16x32_bf16(afrag[2], b, acc[2][c], 0, 0, 0);
      acc[3][c] = __builtin_amdgcn_mfma_f32_16x16x32_bf16(afrag[3], b, acc[3][c], 0, 0, 0);
    }
  }

  float bcol[8];
  for (int c = 0; c < 8; ++c) bcol[c] = bias[c * 16 + n16];

  for (int g = 0; g < 4; ++g) {
    for (int r = 0; r < 4; ++r) {
      int row = rowbase + g * 16 + q * 4 + r;
      if (row >= N) continue;
      for (int c = 0; c < 8; ++c) {
        float v = acc[g][c][r] + bcol[c];
        if (relu) v = v > 0.0f ? v : 0.0f;
        outb[(size_t)row * H_DIM + c * 16 + n16] = f2b(v);
      }
    }
  }
}

// ---------------- final edge dot product (bf16 h2, 16 lanes/edge) -----------
__global__ __launch_bounds__(256) void final_dot(const int* __restrict__ lbl,
                                                 const unsigned short* __restrict__ u2,
                                                 const unsigned short* __restrict__ i2,
                                                 float* __restrict__ out) {
  long t = (long)blockIdx.x * 256 + threadIdx.x;
  int e = (int)(t >> 4);
  if (e >= EL_N) return;
  int lane = (int)(t & 15);
  int lu = lbl[e];
  int li = lbl[EL_N + e];
  u16x8 a = *(const u16x8*)(u2 + (size_t)lu * H_DIM + lane * 8);
  u16x8 b = *(const u16x8*)(i2 + (size_t)li * H_DIM + lane * 8);
  float p = 0.f;
  for (int k = 0; k < 8; ++k) p += b2f(a[k]) * b2f(b[k]);
  for (int off = 8; off > 0; off >>= 1) p += __shfl_down(p, off, 16);
  if (lane == 0) out[e] = p;
}

extern "C" void kernel_launch(void* const* d_in, const int* in_sizes, int n_in,
                              void* d_out, int out_size, void* d_ws, size_t ws_size,
                              hipStream_t stream) {
  const float* user_emb = (const float*)d_in[0];
  const float* item_emb = (const float*)d_in[1];
  const float* w1_ui_l = (const float*)d_in[2];
  const float* w1_ui_r = (const float*)d_in[3];
  const float* w1_iu_l = (const float*)d_in[4];
  const float* w1_iu_r = (const float*)d_in[5];
  const float* w2_ui_l = (const float*)d_in[6];
  const float* w2_ui_r = (const float*)d_in[7];
  const float* w2_iu_l = (const float*)d_in[8];
  const float* w2_iu_r = (const float*)d_in[9];
  const float* b1_ui = (const float*)d_in[10];
  const float* b1_iu = (const float*)d_in[11];
  const float* b2_ui = (const float*)d_in[12];
  const float* b2_iu = (const float*)d_in[13];
  const int* unid = (const int*)d_in[14];
  const int* inid = (const int*)d_in[15];
  const int* e_ui = (const int*)d_in[16];  // row0 users, row1 items
  const int* e_iu = (const int*)d_in[17];  // row0 items, row1 users
  const int* elbl = (const int*)d_in[18];  // row0 users, row1 items
  float* out = (float*)d_out;

  char* ws = (char*)d_ws;
  size_t o = 0;
  auto alloc = [&](size_t bytes) {
    char* p = ws + o;
    o = (o + bytes + 255) & ~(size_t)255;
    return p;
  };
  int* hist = (int*)alloc((size_t)LH_TOT * 4);
  int* hoff = (int*)alloc((size_t)LH_TOT * 4);
  unsigned* bkt = (unsigned*)alloc((size_t)2 * E_N * 4);
  int* csr = (int*)alloc((size_t)2 * E_N * 4);   // u-region [0,E_N), i-region [E_N,2E_N)
  int* cnt_u = (int*)alloc((size_t)U_N * 4);
  int* cnt_i = (int*)alloc((size_t)I_N * 4);
  int* off_u = (int*)alloc((size_t)U_N * 4);
  int* off_i = (int*)alloc((size_t)I_N * 4);
  int* bsum = (int*)alloc(256 * 4);
  unsigned short* ue_b = (unsigned short*)alloc((size_t)U_N * H_DIM * 2);
  unsigned short* ie_b = (unsigned short*)alloc((size_t)I_N * H_DIM * 2);
  unsigned short* agg_u = (unsigned short*)alloc((size_t)U_N * H_DIM * 2);
  unsigned short* agg_i = (unsigned short*)alloc((size_t)I_N * H_DIM * 2);
  unsigned short* h1_u = (unsigned short*)alloc((size_t)U_N * H_DIM * 2);
  unsigned short* h1_i = (unsigned short*)alloc((size_t)I_N * H_DIM * 2);
  unsigned short* h2_u = (unsigned short*)alloc((size_t)U_N * H_DIM * 2);
  unsigned short* h2_i = (unsigned short*)alloc((size_t)I_N * H_DIM * 2);
  short* W2_1u = (short*)alloc(128 * 256 * 2);
  short* W2_1i = (short*)alloc(128 * 256 * 2);
  short* W2_2u = (short*)alloc(128 * 256 * 2);
  short* W2_2i = (short*)alloc(128 * 256 * 2);
  if (o > ws_size) {
    fprintf(stderr, "kernel_launch: ws too small, need %zu have %zu\n", o, ws_size);
    return;
  }

  // 1) fused prep: cvt + weights + coarse histogram
  prep_all<<<CVT_BLK + PREP_BLK + 2 * NBLK, 256, 0, stream>>>(
      user_emb, item_emb, unid, inid, ue_b, ie_b,
      w1_iu_l, w1_iu_r, W2_1u, w1_ui_l, w1_ui_r, W2_1i,
      w2_iu_l, w2_iu_r, W2_2u, w2_ui_l, w2_ui_r, W2_2i,
      e_ui, hist);

  // 2-3) scan of concatenated histogram (p2 folded into p3)
  scan_p1<<<SCAN_BLKS, 256, 0, stream>>>(hist, bsum, LH_TOT);
  scan_p3<<<SCAN_BLKS, 256, 0, stream>>>(hist, bsum, hoff, LH_TOT, SCAN_BLKS);

  // 4) scatter into combined buckets, 5) group -> combined csr + cnt/off
  bin_scatter2<<<2 * NBLK, 256, 0, stream>>>(e_ui, hoff, bkt);
  bin_group2<<<NB_U + NB_I, 256, 0, stream>>>(hoff, bkt, csr, cnt_u, off_u, cnt_i, off_i);

  const int g_blocks = ((U_N + I_N) * 16 + 255) / 256;
  // 6-7) layer 1
  gather_mean2<<<g_blocks, 256, 0, stream>>>(off_u, cnt_u, ie_b, agg_u,
                                             off_i, cnt_i, ue_b, agg_i, csr);
  sage_gemm2<<<NBU2 + NBI2, 256, 0, stream>>>(
      agg_u, ue_b, W2_1u, b1_iu, h1_u,
      agg_i, ie_b, W2_1i, b1_ui, h1_i, 1);

  // 8-9) layer 2 (reuse CSR)
  gather_mean2<<<g_blocks, 256, 0, stream>>>(off_u, cnt_u, h1_i, agg_u,
                                             off_i, cnt_i, h1_u, agg_i, csr);
  sage_gemm2<<<NBU2 + NBI2, 256, 0, stream>>>(
      agg_u, h1_u, W2_2u, b2_iu, h2_u,
      agg_i, h1_i, W2_2i, b2_ui, h2_i, 0);

  // 10) classifier
  final_dot<<<(EL_N * 16 + 255) / 256, 256, 0, stream>>>(elbl, h2_u, h2_i, out);
}